// Round 1
// baseline (237.167 us; speedup 1.0000x reference)
//
#include <hip/hip_runtime.h>
#include <cstddef>

#define D 64

// Kernel 1: Y = X @ W.  One wave per row (grid-strided).
// Lane k holds column k of W in 64 VGPRs; X row is read as wave-uniform
// float4 broadcasts (same address across lanes -> single 16B transaction,
// L1-resident). No LDS, no barriers.
__global__ __launch_bounds__(256) void xw_kernel(
    const float* __restrict__ X, const float* __restrict__ W,
    float* __restrict__ Y, int n_nodes)
{
    const int lane = threadIdx.x & 63;
    float wcol[D];
#pragma unroll
    for (int d = 0; d < D; ++d) wcol[d] = W[d * D + lane];

    const int gwave = (int)((blockIdx.x * blockDim.x + threadIdx.x) >> 6);
    const int nwaves = (int)((gridDim.x * blockDim.x) >> 6);

    for (int row = gwave; row < n_nodes; row += nwaves) {
        const float4* xr = (const float4*)(X + (size_t)row * D);
        float sum = 0.f;
#pragma unroll
        for (int q = 0; q < D / 4; ++q) {
            float4 x = xr[q];
            sum += x.x * wcol[4 * q + 0];
            sum += x.y * wcol[4 * q + 1];
            sum += x.z * wcol[4 * q + 2];
            sum += x.w * wcol[4 * q + 3];
        }
        Y[(size_t)row * D + lane] = sum;
    }
}

// Kernel 2: out[i] = sum_{e in [rp[i], rp[i+1])} Y[ci[e]].
// One wave per row (grid-strided); lane = feature. Coalesced 256B row loads.
// 4-way manual unroll for load-level parallelism.
__global__ __launch_bounds__(256) void gather_kernel(
    const float* __restrict__ Y, const int* __restrict__ rp,
    const int* __restrict__ ci, float* __restrict__ out, int n_nodes)
{
    const int lane = threadIdx.x & 63;
    const int gwave = (int)((blockIdx.x * blockDim.x + threadIdx.x) >> 6);
    const int nwaves = (int)((gridDim.x * blockDim.x) >> 6);

    for (int row = gwave; row < n_nodes; row += nwaves) {
        int e0 = rp[row];
        int e1 = rp[row + 1];
        float a0 = 0.f, a1 = 0.f, a2 = 0.f, a3 = 0.f;
        int e = e0;
        for (; e + 3 < e1; e += 4) {
            int c0 = ci[e + 0];
            int c1 = ci[e + 1];
            int c2 = ci[e + 2];
            int c3 = ci[e + 3];
            a0 += Y[c0 * D + lane];
            a1 += Y[c1 * D + lane];
            a2 += Y[c2 * D + lane];
            a3 += Y[c3 * D + lane];
        }
        for (; e < e1; ++e) a0 += Y[ci[e] * D + lane];
        out[row * D + lane] = (a0 + a1) + (a2 + a3);
    }
}

// Fallback if ws can't hold Y: fused per-row aggregate + shfl-broadcast GEMM.
__global__ __launch_bounds__(256) void fused_kernel(
    const float* __restrict__ X, const float* __restrict__ W,
    const int* __restrict__ rp, const int* __restrict__ ci,
    float* __restrict__ out, int n_nodes)
{
    __shared__ float Wl[D * D];
    for (int i = threadIdx.x; i < D * D; i += 256) Wl[i] = W[i];
    __syncthreads();

    const int lane = threadIdx.x & 63;
    const int gwave = (int)((blockIdx.x * blockDim.x + threadIdx.x) >> 6);
    const int nwaves = (int)((gridDim.x * blockDim.x) >> 6);

    for (int row = gwave; row < n_nodes; row += nwaves) {
        int e0 = rp[row];
        int e1 = rp[row + 1];
        float acc = 0.f;
        for (int e = e0; e < e1; ++e) {
            int col = ci[e];
            acc += X[col * D + lane];
        }
        float sum = 0.f;
#pragma unroll
        for (int d = 0; d < D; ++d) {
            float a = __shfl(acc, d, 64);
            sum += a * Wl[d * D + lane];
        }
        out[row * D + lane] = sum;
    }
}

extern "C" void kernel_launch(void* const* d_in, const int* in_sizes, int n_in,
                              void* d_out, int out_size, void* d_ws, size_t ws_size,
                              hipStream_t stream)
{
    const float* X  = (const float*)d_in[0];   // [n, 64]
    const float* W  = (const float*)d_in[1];   // [64, 64]
    const int*   rp = (const int*)d_in[2];     // [n+1]
    const int*   ci = (const int*)d_in[3];     // [n_edges]
    float* out = (float*)d_out;

    const int n_nodes = in_sizes[2] - 1;
    const size_t y_bytes = (size_t)n_nodes * D * sizeof(float);

    if (ws_size >= y_bytes) {
        float* Y = (float*)d_ws;
        xw_kernel<<<1024, 256, 0, stream>>>(X, W, Y, n_nodes);
        gather_kernel<<<2048, 256, 0, stream>>>(Y, rp, ci, out, n_nodes);
    } else {
        fused_kernel<<<2048, 256, 0, stream>>>(X, W, rp, ci, out, n_nodes);
    }
}

// Round 2
// 211.089 us; speedup vs baseline: 1.1235x; 1.1235x over previous
//
#include <hip/hip_runtime.h>
#include <cstdint>
#include <cstddef>

#define D 64

// round-to-nearest-even fp32 -> bf16 (returns bf16 bits in low 16)
__device__ __forceinline__ uint32_t rne_bf16(float f) {
    uint32_t x = __float_as_uint(f);
    return (x + 0x7fffu + ((x >> 16) & 1u)) >> 16;
}

// Kernel 1: Y2 = pack_bf16(X @ W).  One wave per row (grid-strided).
// Lane k holds column k of W in VGPRs; X row read as wave-uniform float4
// broadcasts. Output packed as u32 = (bf16 feat 2p) | (bf16 feat 2p+1)<<16,
// 32 u32 per row (128 B rows).
__global__ __launch_bounds__(256) void xw_bf16_kernel(
    const float* __restrict__ X, const float* __restrict__ W,
    uint32_t* __restrict__ Y2, int n_nodes)
{
    const int lane = threadIdx.x & 63;
    float wcol[D];
#pragma unroll
    for (int d = 0; d < D; ++d) wcol[d] = W[d * D + lane];

    const int gwave = (int)((blockIdx.x * blockDim.x + threadIdx.x) >> 6);
    const int nwaves = (int)((gridDim.x * blockDim.x) >> 6);

    for (int row = gwave; row < n_nodes; row += nwaves) {
        const float4* xr = (const float4*)(X + (size_t)row * D);
        float sum = 0.f;
#pragma unroll
        for (int q = 0; q < D / 4; ++q) {
            float4 x = xr[q];
            sum += x.x * wcol[4 * q + 0];
            sum += x.y * wcol[4 * q + 1];
            sum += x.z * wcol[4 * q + 2];
            sum += x.w * wcol[4 * q + 3];
        }
        // pack feature pairs: even lane takes (own, lane+1's)
        float other = __shfl_xor(sum, 1, 64);
        if ((lane & 1) == 0) {
            uint32_t u = rne_bf16(sum) | (rne_bf16(other) << 16);
            Y2[(size_t)row * 32 + (lane >> 1)] = u;  // 32 lanes, consecutive -> coalesced
        }
    }
}

// Kernel 2: out[i] = sum_{e} Y[ci[e]] with Y in packed bf16.
// One wave per row. half = lane>>5 processes even/odd edges; p = lane&31 is
// the feature-pair index. 8 edges in flight (4 gather instrs x 2 edges each).
__global__ __launch_bounds__(256) void gather_bf16_kernel(
    const uint32_t* __restrict__ Y2, const int* __restrict__ rp,
    const int* __restrict__ ci, float* __restrict__ out, int n_nodes)
{
    const int lane = threadIdx.x & 63;
    const int half = lane >> 5;
    const int p    = lane & 31;
    const int row  = (int)((blockIdx.x * blockDim.x + threadIdx.x) >> 6);
    if (row >= n_nodes) return;

    const int e0 = rp[row];
    const int e1 = rp[row + 1];

    float a0 = 0.f, a1 = 0.f, b0 = 0.f, b1 = 0.f;
    float c0 = 0.f, c1 = 0.f, d0 = 0.f, d1 = 0.f;

    int e = e0;
    for (; e + 8 <= e1; e += 8) {
        int i0 = ci[e     + half];
        int i1 = ci[e + 2 + half];
        int i2 = ci[e + 4 + half];
        int i3 = ci[e + 6 + half];
        uint32_t u0 = Y2[(size_t)i0 * 32 + p];
        uint32_t u1 = Y2[(size_t)i1 * 32 + p];
        uint32_t u2 = Y2[(size_t)i2 * 32 + p];
        uint32_t u3 = Y2[(size_t)i3 * 32 + p];
        a0 += __uint_as_float(u0 << 16); a1 += __uint_as_float(u0 & 0xffff0000u);
        b0 += __uint_as_float(u1 << 16); b1 += __uint_as_float(u1 & 0xffff0000u);
        c0 += __uint_as_float(u2 << 16); c1 += __uint_as_float(u2 & 0xffff0000u);
        d0 += __uint_as_float(u3 << 16); d1 += __uint_as_float(u3 & 0xffff0000u);
    }
    for (; e + 2 <= e1; e += 2) {
        int i0 = ci[e + half];
        uint32_t u0 = Y2[(size_t)i0 * 32 + p];
        a0 += __uint_as_float(u0 << 16); a1 += __uint_as_float(u0 & 0xffff0000u);
    }
    if (e < e1 && half == 0) {  // odd last edge: even-half only
        uint32_t u0 = Y2[(size_t)ci[e] * 32 + p];
        a0 += __uint_as_float(u0 << 16); a1 += __uint_as_float(u0 & 0xffff0000u);
    }

    float r0 = (a0 + b0) + (c0 + d0);
    float r1 = (a1 + b1) + (c1 + d1);
    r0 += __shfl_xor(r0, 32, 64);  // combine even/odd-edge halves (same p)
    r1 += __shfl_xor(r1, 32, 64);
    if (half == 0) {
        float2* o = (float2*)(out + (size_t)row * D);
        o[p] = make_float2(r0, r1);  // 32 lanes x 8 B = 256 B coalesced
    }
}

// Fallback if ws can't hold Y2: fused per-row aggregate + shfl-broadcast GEMM.
__global__ __launch_bounds__(256) void fused_kernel(
    const float* __restrict__ X, const float* __restrict__ W,
    const int* __restrict__ rp, const int* __restrict__ ci,
    float* __restrict__ out, int n_nodes)
{
    __shared__ float Wl[D * D];
    for (int i = threadIdx.x; i < D * D; i += 256) Wl[i] = W[i];
    __syncthreads();

    const int lane = threadIdx.x & 63;
    const int gwave = (int)((blockIdx.x * blockDim.x + threadIdx.x) >> 6);
    const int nwaves = (int)((gridDim.x * blockDim.x) >> 6);

    for (int row = gwave; row < n_nodes; row += nwaves) {
        int e0 = rp[row];
        int e1 = rp[row + 1];
        float acc = 0.f;
        for (int e = e0; e < e1; ++e) acc += X[ci[e] * D + lane];
        float sum = 0.f;
#pragma unroll
        for (int d = 0; d < D; ++d) {
            float a = __shfl(acc, d, 64);
            sum += a * Wl[d * D + lane];
        }
        out[row * D + lane] = sum;
    }
}

extern "C" void kernel_launch(void* const* d_in, const int* in_sizes, int n_in,
                              void* d_out, int out_size, void* d_ws, size_t ws_size,
                              hipStream_t stream)
{
    const float* X  = (const float*)d_in[0];   // [n, 64]
    const float* W  = (const float*)d_in[1];   // [64, 64]
    const int*   rp = (const int*)d_in[2];     // [n+1]
    const int*   ci = (const int*)d_in[3];     // [n_edges]
    float* out = (float*)d_out;

    const int n_nodes = in_sizes[2] - 1;
    const size_t y2_bytes = (size_t)n_nodes * 32 * sizeof(uint32_t);

    if (ws_size >= y2_bytes) {
        uint32_t* Y2 = (uint32_t*)d_ws;
        xw_bf16_kernel<<<2048, 256, 0, stream>>>(X, W, Y2, n_nodes);
        const int gather_blocks = (n_nodes + 3) / 4;  // one wave per row
        gather_bf16_kernel<<<gather_blocks, 256, 0, stream>>>(Y2, rp, ci, out, n_nodes);
    } else {
        fused_kernel<<<2048, 256, 0, stream>>>(X, W, rp, ci, out, n_nodes);
    }
}

// Round 4
// 162.870 us; speedup vs baseline: 1.4562x; 1.2961x over previous
//
#include <hip/hip_runtime.h>
#include <cstdint>
#include <cstddef>

#define D 64

typedef float f32x4 __attribute__((ext_vector_type(4)));

// round-to-nearest-even fp32 -> bf16 (bits in low 16)
__device__ __forceinline__ uint32_t rne_bf16(float f) {
    uint32_t x = __float_as_uint(f);
    return (x + 0x7fffu + ((x >> 16) & 1u)) >> 16;
}
__device__ __forceinline__ float bf16lo(uint32_t u) { return __uint_as_float(u << 16); }
__device__ __forceinline__ float bf16hi(uint32_t u) { return __uint_as_float(u & 0xffff0000u); }

// Kernel 1: Y2 = pack_bf16(X @ W).  One wave per row (grid-strided).
// lane = output feature. X row loaded as ONE coalesced 256B wave load;
// X[row][d] broadcast to all lanes via v_readlane (compile-time index),
// multiplied against register-resident W column. 4 partial sums break the
// FMA dependency chain.
__global__ __launch_bounds__(256) void xw_bf16_kernel(
    const float* __restrict__ X, const float* __restrict__ W,
    uint32_t* __restrict__ Y2, int n_nodes)
{
    const int lane = threadIdx.x & 63;
    float wcol[D];
#pragma unroll
    for (int d = 0; d < D; ++d) wcol[d] = W[d * D + lane];

    const int gwave = (int)((blockIdx.x * blockDim.x + threadIdx.x) >> 6);
    const int nwaves = (int)((gridDim.x * blockDim.x) >> 6);

    for (int row = gwave; row < n_nodes; row += nwaves) {
        const int xb = __float_as_int(X[(size_t)row * D + lane]);  // coalesced 256B
        float s0 = 0.f, s1 = 0.f, s2 = 0.f, s3 = 0.f;
#pragma unroll
        for (int d = 0; d < D; d += 4) {
            s0 += __int_as_float(__builtin_amdgcn_readlane(xb, d + 0)) * wcol[d + 0];
            s1 += __int_as_float(__builtin_amdgcn_readlane(xb, d + 1)) * wcol[d + 1];
            s2 += __int_as_float(__builtin_amdgcn_readlane(xb, d + 2)) * wcol[d + 2];
            s3 += __int_as_float(__builtin_amdgcn_readlane(xb, d + 3)) * wcol[d + 3];
        }
        const float sum = (s0 + s1) + (s2 + s3);
        const float other = __shfl_xor(sum, 1, 64);
        if ((lane & 1) == 0) {
            uint32_t u = rne_bf16(sum) | (rne_bf16(other) << 16);
            Y2[(size_t)row * 32 + (lane >> 1)] = u;  // 32 lanes x 4B coalesced
        }
    }
}

// Kernel 2: out[i] = sum_e Y[ci[e]], Y packed bf16 (128B rows).
// One wave per row. q = lane>>4 selects edge within a group of 4;
// p = lane&15 is the feature-quad (uint2 = 4 bf16 features).
// 4 edges per load instruction x 4-deep unroll = 16 edges in flight.
__global__ __launch_bounds__(256) void gather_bf16_kernel(
    const uint32_t* __restrict__ Y2, const int* __restrict__ rp,
    const int* __restrict__ ci, float* __restrict__ out, int n_nodes)
{
    const int lane = threadIdx.x & 63;
    const int q = lane >> 4;
    const int p = lane & 15;
    const int row = (int)((blockIdx.x * blockDim.x + threadIdx.x) >> 6);
    if (row >= n_nodes) return;

    const int e0 = rp[row];
    const int e1 = rp[row + 1];

    float a0 = 0.f, a1 = 0.f, a2 = 0.f, a3 = 0.f;
    float b0 = 0.f, b1 = 0.f, b2 = 0.f, b3 = 0.f;
    float c0 = 0.f, c1 = 0.f, c2 = 0.f, c3 = 0.f;
    float d0 = 0.f, d1 = 0.f, d2 = 0.f, d3 = 0.f;

    int e = e0;
    for (; e + 16 <= e1; e += 16) {
        const int i0 = ci[e + q];
        const int i1 = ci[e + 4 + q];
        const int i2 = ci[e + 8 + q];
        const int i3 = ci[e + 12 + q];
        const uint2 u0 = *(const uint2*)(Y2 + (size_t)i0 * 32 + p * 2);
        const uint2 u1 = *(const uint2*)(Y2 + (size_t)i1 * 32 + p * 2);
        const uint2 u2 = *(const uint2*)(Y2 + (size_t)i2 * 32 + p * 2);
        const uint2 u3 = *(const uint2*)(Y2 + (size_t)i3 * 32 + p * 2);
        a0 += bf16lo(u0.x); a1 += bf16hi(u0.x); a2 += bf16lo(u0.y); a3 += bf16hi(u0.y);
        b0 += bf16lo(u1.x); b1 += bf16hi(u1.x); b2 += bf16lo(u1.y); b3 += bf16hi(u1.y);
        c0 += bf16lo(u2.x); c1 += bf16hi(u2.x); c2 += bf16lo(u2.y); c3 += bf16hi(u2.y);
        d0 += bf16lo(u3.x); d1 += bf16hi(u3.x); d2 += bf16lo(u3.y); d3 += bf16hi(u3.y);
    }
    for (; e + 4 <= e1; e += 4) {
        const int i0 = ci[e + q];
        const uint2 u0 = *(const uint2*)(Y2 + (size_t)i0 * 32 + p * 2);
        a0 += bf16lo(u0.x); a1 += bf16hi(u0.x); a2 += bf16lo(u0.y); a3 += bf16hi(u0.y);
    }
    const int rem = e1 - e;
    if (q < rem) {
        const int i0 = ci[e + q];
        const uint2 u0 = *(const uint2*)(Y2 + (size_t)i0 * 32 + p * 2);
        a0 += bf16lo(u0.x); a1 += bf16hi(u0.x); a2 += bf16lo(u0.y); a3 += bf16hi(u0.y);
    }

    float r0 = (a0 + b0) + (c0 + d0);
    float r1 = (a1 + b1) + (c1 + d1);
    float r2 = (a2 + b2) + (c2 + d2);
    float r3 = (a3 + b3) + (c3 + d3);
    // reduce across the 4 edge-quarters (lanes with equal p)
    r0 += __shfl_xor(r0, 16, 64); r1 += __shfl_xor(r1, 16, 64);
    r2 += __shfl_xor(r2, 16, 64); r3 += __shfl_xor(r3, 16, 64);
    r0 += __shfl_xor(r0, 32, 64); r1 += __shfl_xor(r1, 32, 64);
    r2 += __shfl_xor(r2, 32, 64); r3 += __shfl_xor(r3, 32, 64);

    if (q == 0) {
        f32x4 v = { r0, r1, r2, r3 };
        __builtin_nontemporal_store(v, (f32x4*)(out + (size_t)row * D + p * 4));
    }
}

// Fallback if ws can't hold Y2: fused per-row aggregate + shfl-broadcast GEMM.
__global__ __launch_bounds__(256) void fused_kernel(
    const float* __restrict__ X, const float* __restrict__ W,
    const int* __restrict__ rp, const int* __restrict__ ci,
    float* __restrict__ out, int n_nodes)
{
    __shared__ float Wl[D * D];
    for (int i = threadIdx.x; i < D * D; i += 256) Wl[i] = W[i];
    __syncthreads();

    const int lane = threadIdx.x & 63;
    const int gwave = (int)((blockIdx.x * blockDim.x + threadIdx.x) >> 6);
    const int nwaves = (int)((gridDim.x * blockDim.x) >> 6);

    for (int row = gwave; row < n_nodes; row += nwaves) {
        int e0 = rp[row];
        int e1 = rp[row + 1];
        float acc = 0.f;
        for (int e = e0; e < e1; ++e) acc += X[ci[e] * D + lane];
        float sum = 0.f;
#pragma unroll
        for (int d = 0; d < D; ++d) {
            float a = __shfl(acc, d, 64);
            sum += a * Wl[d * D + lane];
        }
        out[row * D + lane] = sum;
    }
}

extern "C" void kernel_launch(void* const* d_in, const int* in_sizes, int n_in,
                              void* d_out, int out_size, void* d_ws, size_t ws_size,
                              hipStream_t stream)
{
    const float* X  = (const float*)d_in[0];   // [n, 64]
    const float* W  = (const float*)d_in[1];   // [64, 64]
    const int*   rp = (const int*)d_in[2];     // [n+1]
    const int*   ci = (const int*)d_in[3];     // [n_edges]
    float* out = (float*)d_out;

    const int n_nodes = in_sizes[2] - 1;
    const size_t y2_bytes = (size_t)n_nodes * 32 * sizeof(uint32_t);

    if (ws_size >= y2_bytes) {
        uint32_t* Y2 = (uint32_t*)d_ws;
        xw_bf16_kernel<<<2048, 256, 0, stream>>>(X, W, Y2, n_nodes);
        const int gather_blocks = (n_nodes + 3) / 4;  // one wave per row
        gather_bf16_kernel<<<gather_blocks, 256, 0, stream>>>(Y2, rp, ci, out, n_nodes);
    } else {
        fused_kernel<<<2048, 256, 0, stream>>>(X, W, rp, ci, out, n_nodes);
    }
}